// Round 8
// baseline (492.826 us; speedup 1.0000x reference)
//
#include <hip/hip_runtime.h>
#include <hip/hip_bf16.h>

// ---------------------------------------------------------------------------
// NHRepNet fused forward, Round 22: Gch=4 x Gpt=2, asymmetric halves (64/32).
//
// Established (R1-R21):
//  - R17/R19 (96-pt, kk-sliced A/B stagger, Gch=8): 103.4-104.4us. Interleave
//    proven (+12 vs phase-serial).
//  - R20 (poly softplus): VALU -11us real, dur NULL. R21 (LDS-only barrier):
//    NULL (no cross-region vmcnt in flight -> drain was free).
//  - ARITHMETIC: LDS pipe is the binding stream. Per stag region/CU:
//    384 b128 x 12cyc ~= 4600 cyc LDS vs ~930 cyc MFMA (5x oversubscribed).
//    Whole kernel ~68us pure LDS-pipe occupancy of 105us wall. Only lever of
//    size: cut Gch (act-row readers/wave).
//  - R18 closed Gch=4 at acc[4][3] dual = 96 AGPR. THIS kernel reopens it
//    with asymmetric halves: A=64pt, B=32pt -> dual acc 4x2+4x1 = 48 AGPR
//    (R17's proven budget).
//
// R22: 8 waves = 4 ch-groups (64 ch) x 2 pt-groups. Per layer per block:
//  B-LDS 393->197KB (LDS stream ~36us); A-traffic x2 = 1.8GB but L2-resident
//  (FETCH flat; ~21us/CU VMEM stream); same 96-pt tile, 2 bar/layer, plain
//  __syncthreads (R21 null), poly softplus kept (VALU co-critical now).
//  Slices: build-A region retires B's 4, build-B retires A's 8.
// Gates: BANK_CONFLICT ~halves (mechanism); WRITE<=20MB (spill); dur 88-96.
// ---------------------------------------------------------------------------

using bf16x8 = __attribute__((ext_vector_type(8))) __bf16;
using f32x4  = __attribute__((ext_vector_type(4))) float;

#define LDA 264   // padded activation row stride (bf16)

#define OFFW0 0
#define OFFW1 8192
#define OFFW7 401408
#define WSB_BYTE_OFF 811008   // fp32 bias region
#define OFFB7 1792            // L0..L6 at l*256; L7 at 1792 (16 floats, padded)

#define SCALE_T2 144.26950408889634f      // 100*log2(e)
#define INV_SQRT2 0.70710678118654752f
#define LN2_100 0.0069314718055994531f    // ln2/100

__device__ __forceinline__ float fast_exp2(float x) {
#if __has_builtin(__builtin_amdgcn_exp2f)
    return __builtin_amdgcn_exp2f(x);
#else
    return exp2f(x);
#endif
}

// a2 = max(t2,0) + log2(1 + 2^-|t2|)   (t2-domain; scales folded into weights)
// log2(1+e), e in [0,1], as cubic through origin (R20): 1 trans + 5 VALU.
__device__ __forceinline__ float softplus_t2(float t2) {
    float e = fast_exp2(-fabsf(t2));
    float p = __builtin_fmaf(e, 0.20568f, -0.64838f);
    p = __builtin_fmaf(e, p, 1.4427f);
    return fmaxf(t2, 0.0f) + e * p;
}

__device__ __forceinline__ unsigned short bf16_rne(float f) {
    unsigned int u = __float_as_uint(f);
    unsigned int r = u + 0x7FFFu + ((u >> 16) & 1u);
    return (unsigned short)(r >> 16);
}

// ---------------------------------------------------------------------------
// Wave (c,p): c = channel-group 0..3 (owns ch [c*64, c*64+64), strips i=0..3),
// p = point-group 0..1 (owns pts [p*NT*16, (p+1)*NT*16) of the half).
// ---------------------------------------------------------------------------

// Plain MFMA half-build (layer 0 only, KK=1).
template <int KK, int NT>
__device__ __forceinline__ void mfma_group(
    const unsigned short* __restrict__ wfrag,
    const float* __restrict__ bias,
    const unsigned short* act,
    f32x4 (&acc)[4][NT], int c, int p, int lane)
{
    const int quad = lane >> 4;
    const int l15  = lane & 15;
    const int row0 = p * NT * 16 + l15;

#pragma unroll
    for (int i = 0; i < 4; ++i) {
        const int chb = (c * 4 + i) * 16 + quad * 4;
        const float4 b4 = *(const float4*)(bias + chb);
#pragma unroll
        for (int nt = 0; nt < NT; ++nt)
            acc[i][nt] = f32x4{b4.x, b4.y, b4.z, b4.w};
    }

    const unsigned short* wbase = wfrag + (c * 4 * KK * 64 + lane) * 8;

#pragma unroll
    for (int kk = 0; kk < KK; ++kk) {
        bf16x8 bfr[NT];
#pragma unroll
        for (int nt = 0; nt < NT; ++nt)
            bfr[nt] = *(const bf16x8*)(act + (row0 + nt * 16) * LDA + kk * 32 + quad * 8);
#pragma unroll
        for (int i = 0; i < 4; ++i) {
            bf16x8 a = *(const bf16x8*)(wbase + (i * KK + kk) * 512);
#pragma unroll
            for (int nt = 0; nt < NT; ++nt)
                acc[i][nt] = __builtin_amdgcn_mfma_f32_16x16x32_bf16(a, bfr[nt], acc[i][nt], 0, 0, 0);
        }
    }
}

// Full epilogue of a half (used where no mfma to hide under).
template <int NT>
__device__ __forceinline__ void epi_group_full(
    f32x4 (&acc)[4][NT], unsigned short* act, const float* xst,
    int c, int p, int lane, bool splice)
{
    const int quad = lane >> 4;
    const int l15  = lane & 15;
    const int row0 = p * NT * 16 + l15;
#pragma unroll
    for (int i = 0; i < 4; ++i) {
        const int chb = (c * 4 + i) * 16 + quad * 4;
#pragma unroll
        for (int nt = 0; nt < NT; ++nt) {
            const int pt = row0 + nt * 16;
            float vv[4];
#pragma unroll
            for (int r = 0; r < 4; ++r)
                vv[r] = softplus_t2(acc[i][nt][r]);
            if (splice && chb == 252) {   // ch 253..255 <- raw x (c=3,i=3,q=3)
                vv[1] = xst[pt * 4 + 0];
                vv[2] = xst[pt * 4 + 1];
                vv[3] = xst[pt * 4 + 2];
            }
            __hip_bfloat162 p01 = __float22bfloat162_rn(float2{vv[0], vv[1]});
            __hip_bfloat162 p23 = __float22bfloat162_rn(float2{vv[2], vv[3]});
            uint2 pk;
            pk.x = *(unsigned int*)&p01;
            pk.y = *(unsigned int*)&p23;
            *(uint2*)(act + pt * LDA + chb) = pk;
        }
    }
}

// ---------------------------------------------------------------------------
// Staggered region: build accX (half X, NTX tiles/wave) while retiring accY
// (other half's previous-layer preacts), one slice per kk while kk < 4*NTY.
// Slice (i,nt) = (kk&3, kk>>2) — compile-time under full unroll. Slice VALU
// sits between bfr ds_reads and the afr-load/MFMA chain.
// ---------------------------------------------------------------------------
template <int KK, int NTX, int NTY>
__device__ __forceinline__ void stag_region(
    const unsigned short* __restrict__ wfrag,
    const float* __restrict__ bias,
    const unsigned short* __restrict__ actX,
    unsigned short* actY,
    f32x4 (&accX)[4][NTX], f32x4 (&accY)[4][NTY],
    const float* xstY, bool splice, int c, int p, int lane)
{
    const int quad = lane >> 4;
    const int l15  = lane & 15;
    const int rowX0 = p * NTX * 16 + l15;
    const int rowY0 = p * NTY * 16 + l15;

#pragma unroll
    for (int i = 0; i < 4; ++i) {
        const int chb = (c * 4 + i) * 16 + quad * 4;
        const float4 b4 = *(const float4*)(bias + chb);
#pragma unroll
        for (int nt = 0; nt < NTX; ++nt)
            accX[i][nt] = f32x4{b4.x, b4.y, b4.z, b4.w};
    }

    const unsigned short* wbase = wfrag + (c * 4 * KK * 64 + lane) * 8;

#pragma unroll
    for (int kk = 0; kk < KK; ++kk) {
        bf16x8 bfr[NTX];
#pragma unroll
        for (int nt = 0; nt < NTX; ++nt)
            bfr[nt] = *(const bf16x8*)(actX + (rowX0 + nt * 16) * LDA + kk * 32 + quad * 8);

        if (kk < 4 * NTY) {   // one retired slice of half Y (compile-time idx)
            const int i  = kk & 3;
            const int nt = kk >> 2;
            const int chb = (c * 4 + i) * 16 + quad * 4;
            const int pt  = rowY0 + nt * 16;
            float vv[4];
#pragma unroll
            for (int r = 0; r < 4; ++r)
                vv[r] = softplus_t2(accY[i][nt][r]);
            if (splice && chb == 252) {   // ch 253..255 <- raw x
                vv[1] = xstY[pt * 4 + 0];
                vv[2] = xstY[pt * 4 + 1];
                vv[3] = xstY[pt * 4 + 2];
            }
            __hip_bfloat162 p01 = __float22bfloat162_rn(float2{vv[0], vv[1]});
            __hip_bfloat162 p23 = __float22bfloat162_rn(float2{vv[2], vv[3]});
            uint2 pk;
            pk.x = *(unsigned int*)&p01;
            pk.y = *(unsigned int*)&p23;
            *(uint2*)(actY + pt * LDA + chb) = pk;
        }

#pragma unroll
        for (int i = 0; i < 4; ++i) {
            bf16x8 a = *(const bf16x8*)(wbase + (i * KK + kk) * 512);
#pragma unroll
            for (int nt = 0; nt < NTX; ++nt)
                accX[i][nt] = __builtin_amdgcn_mfma_f32_16x16x32_bf16(a, bfr[nt], accX[i][nt], 0, 0, 0);
        }
    }
}

// ---------------------------------------------------------------------------
// Layer 7 (256->8) for one 16-pt row block at row0; reduce + CSG + store.
// ---------------------------------------------------------------------------
__device__ __forceinline__ void l7_part(
    const unsigned short* act, const unsigned short* __restrict__ w7,
    const float* __restrict__ wsB, float* __restrict__ out,
    int row0, int ptg0, int npts, int lane)
{
    const int quad = lane >> 4, l15 = lane & 15;
    const float4 b4 = *(const float4*)(wsB + OFFB7 + quad * 4);  // quads>=2: zeros
    f32x4 acc = f32x4{b4.x, b4.y, b4.z, b4.w};
#pragma unroll
    for (int kk = 0; kk < 8; ++kk) {
        bf16x8 bfr = *(const bf16x8*)(act + (row0 + l15) * LDA + kk * 32 + quad * 8);
        bf16x8 afr = *(const bf16x8*)(w7 + (kk * 64 + lane) * 8);
        acc = __builtin_amdgcn_mfma_f32_16x16x32_bf16(afr, bfr, acc, 0, 0, 0);
    }
    // quad0 lanes hold ch0-3, quad1 ch4-7 for pt = row0+l15
    float u0 = __shfl(acc[0], l15 + 16);
    float u1 = __shfl(acc[1], l15 + 16);
    float u2 = __shfl(acc[2], l15 + 16);
    float u3 = __shfl(acc[3], l15 + 16);
    if (quad == 0) {
        const int ptg = ptg0 + l15;
        if (ptg < npts) {
            const float v0 = acc[0], v1 = acc[1], v2 = acc[2], v3 = acc[3];
            const float v4 = u0, v5 = u1, v6 = u2, v7 = u3;
            const float m23   = fminf(v2, v3);
            const float m67   = fmaxf(v6, v7);
            const float m4567 = fminf(fminf(v4, v5), m67);
            const float h     = fmaxf(fmaxf(v0, v1), fmaxf(m23, m4567));
            float* o = out + (long)ptg * 9;
            o[0] = h;
            o[1] = v0; o[2] = v1; o[3] = v2; o[4] = v3;
            o[5] = v4; o[6] = v5; o[7] = v6; o[8] = v7;
        }
    }
}

// ---------------------------------------------------------------------------
// Full network for one tile of 2*(NTA+NTB)*16 points:
// <2,1> -> 64+32 = 96-pt big blocks; <1,1> -> 32+32 = 64-pt tail blocks.
// Two staggered in-place halves A (rows 0..HA) and B (rows HA..HA+HB).
// Schedule:
//   stage; bar
//   mfma_A(0); bar
//   mfma_B(0); epi_A(0); bar
//   l=1..6:  stag[build A(l) + retire B's 4*NTB slices (l-1)]; bar
//            stag[build B(l) + retire A's 4*NTA slices (l)];   bar
//   [L7(A) waves<2*NTA || epi_B(6)]; bar;  L7(B) waves<2*NTB
// ---------------------------------------------------------------------------
template <int NTA, int NTB>
__device__ __forceinline__ void run_net(
    const float* __restrict__ x, float* __restrict__ out,
    const unsigned short* __restrict__ wsW, const float* __restrict__ wsB,
    unsigned short* act, float* xst,
    int base_pt, int npts, int tid)
{
    const int wave = tid >> 6, lane = tid & 63;
    const int c = wave >> 1, p = wave & 1;
    constexpr int HA = 2 * NTA * 16;
    constexpr int HB = 2 * NTB * 16;
    constexpr int TP = HA + HB;

    // stage x into act channels 0..2, zero-pad to 32 (K-pad for layer 0)
    for (int i = tid; i < TP * 32; i += 512) {
        const int pt = i >> 5, ch = i & 31;
        const int ptg = base_pt + pt;
        float v = 0.0f;
        if (ch < 3 && ptg < npts) v = x[ptg * 3 + ch];
        act[pt * LDA + ch] = bf16_rne(v);
        if (ch < 4) xst[pt * 4 + ch] = (ch < 3) ? v : 0.0f;
    }
    __syncthreads();

    unsigned short* actA = act;
    unsigned short* actB = act + HA * LDA;
    const float* xstA = xst;
    const float* xstB = xst + HA * 4;

    f32x4 accA[4][NTA], accB[4][NTB];

    // layer 0 (KK=1, tiny): A alone, then B with serial epi_A
    mfma_group<1, NTA>(wsW + OFFW0, wsB, actA, accA, c, p, lane);
    __syncthreads();
    mfma_group<1, NTB>(wsW + OFFW0, wsB, actB, accB, c, p, lane);
    epi_group_full<NTA>(accA, actA, xstA, c, p, lane, false);
    __syncthreads();

    // layers 1..6, two staggered regions each
#pragma unroll 1
    for (int l = 1; l <= 6; ++l) {
        const unsigned short* Wl = wsW + OFFW1 + (l - 1) * 65536;
        const float* bl = wsB + l * 256;

        // build A(l) + retire accB(l-1)  (splice when l-1 == 3)
        stag_region<8, NTA, NTB>(Wl, bl, actA, actB, accA, accB, xstB,
                                 l == 4, c, p, lane);
        __syncthreads();

        // build B(l) + retire accA(l)    (splice when l == 3)
        stag_region<8, NTB, NTA>(Wl, bl, actB, actA, accB, accA, xstA,
                                 l == 3, c, p, lane);
        __syncthreads();
    }

    // [L7(A) || epi_B(6)]: actA finalized last region; epi writes actB only.
    if (wave < 2 * NTA)
        l7_part(act, wsW + OFFW7, wsB, out, wave * 16, base_pt + wave * 16,
                npts, lane);
    epi_group_full<NTB>(accB, actB, xstB, c, p, lane, false);
    __syncthreads();

    // L7(B)
    if (wave < 2 * NTB)
        l7_part(act, wsW + OFFW7, wsB, out,
                HA + wave * 16, base_pt + HA + wave * 16, npts, lane);
}

__global__ __launch_bounds__(512, 4)
void nhrep_main(const float* __restrict__ x, float* __restrict__ out,
                const unsigned short* __restrict__ wsW,
                const float* __restrict__ wsB, int npts, int nbig)
{
    __shared__ unsigned short act[96 * LDA];   // 50688 B
    __shared__ float xst[96 * 4];              // 1536 B -> 52224 B total
    const int b = blockIdx.x;
    if (b < nbig) {
        run_net<2, 1>(x, out, wsW, wsB, act, xst, b * 96, npts, threadIdx.x);
    } else {
        run_net<1, 1>(x, out, wsW, wsB, act, xst,
                      nbig * 96 + (b - nbig) * 64, npts, threadIdx.x);
    }
}

// ---------------------------------------------------------------------------
// Fused prepack with scale folding (proven since R4, identity k-mapping).
// Frag (mt,kk,lane,j) = scale(l,k) * W^T[mt*16+(lane&15)][kk*32+(lane>>4)*8+j]
// Layout is mt-absolute -> unchanged for the Gch=4 wave mapping.
// ---------------------------------------------------------------------------
struct PackArgs {
    const float* W[8];
    const float* b[8];
};

#define TOTAL_FRAGS 50688
#define TOTAL_BIAS  1808

__global__ void prepack_all(PackArgs args, unsigned short* __restrict__ dstW,
                            float* __restrict__ dstB)
{
    const int t = blockIdx.x * blockDim.x + threadIdx.x;
    const int FB[9]  = {0, 1024, 9216, 17408, 25600, 33792, 41984, 50176, 50688};
    const int KKs[8] = {1, 8, 8, 8, 8, 8, 8, 8};
    const int ind[8] = {3, 256, 256, 256, 256, 256, 256, 256};
    const int outd[8]= {256, 256, 256, 253, 256, 256, 256, 8};

    if (t < TOTAL_FRAGS) {
        int l = 0;
        while (t >= FB[l + 1]) ++l;
        const int f    = t - FB[l];
        const int lane = f & 63;
        const int kk   = (f >> 6) % KKs[l];
        const int mt   = f / (64 * KKs[l]);
        const int o    = mt * 16 + (lane & 15);
        const int kb   = kk * 32 + (lane >> 4) * 8;
        const float* W = args.W[l];
        const int in_d = ind[l], out_d = outd[l];

        unsigned short v[8];
#pragma unroll
        for (int j = 0; j < 8; ++j) {
            const int k = kb + j;
            float w = 0.0f;
            if (k < in_d && o < out_d) {
                float sc = 1.0f;
                if (l == 0) sc = SCALE_T2;
                else if (l == 4) sc = (k < 253) ? INV_SQRT2 : (SCALE_T2 * INV_SQRT2);
                else if (l == 7) sc = LN2_100;
                w = W[k * out_d + o] * sc;
            }
            unsigned int u = __float_as_uint(w);
            v[j] = (unsigned short)((u + 0x7FFFu + ((u >> 16) & 1u)) >> 16);
        }
        uint4 p;
        p.x = (unsigned int)v[0] | ((unsigned int)v[1] << 16);
        p.y = (unsigned int)v[2] | ((unsigned int)v[3] << 16);
        p.z = (unsigned int)v[4] | ((unsigned int)v[5] << 16);
        p.w = (unsigned int)v[6] | ((unsigned int)v[7] << 16);
        *(uint4*)(dstW + (long)t * 8) = p;
    } else if (t < TOTAL_FRAGS + TOTAL_BIAS) {
        const int u = t - TOTAL_FRAGS;
        const int l = (u < 1792) ? (u >> 8) : 7;
        const int idx = (l < 7) ? (u & 255) : (u - 1792);
        const float sc = (l < 7) ? SCALE_T2 : 1.0f;   // b7 stays in output units
        dstB[u] = (idx < outd[l]) ? args.b[l][idx] * sc : 0.0f;
    }
}

extern "C" void kernel_launch(void* const* d_in, const int* in_sizes, int n_in,
                              void* d_out, int out_size, void* d_ws, size_t ws_size,
                              hipStream_t stream)
{
    const float* x = (const float*)d_in[0];
    unsigned short* wsW = (unsigned short*)d_ws;
    float* wsB = (float*)((char*)d_ws + WSB_BYTE_OFF);

    PackArgs pa;
    for (int l = 0; l < 8; ++l) {
        pa.W[l] = (const float*)d_in[1 + 2 * l];
        pa.b[l] = (const float*)d_in[2 + 2 * l];
    }
    const int ptot = TOTAL_FRAGS + TOTAL_BIAS;
    prepack_all<<<(ptot + 255) / 256, 256, 0, stream>>>(pa, wsW, wsB);

    const int npts = in_sizes[0] / 3;            // 100000
    // Mixed grid: 96-pt blocks for the bulk, 64-pt blocks for the drain tail.
    int nbig, nsmall;
    const int tail_pts = 16384;
    if (npts > tail_pts) {
        nbig = (npts - tail_pts + 95) / 96;      // 872
        const int base_small = nbig * 96;
        nsmall = (npts - base_small + 63) / 64;  // ~255
    } else {
        nbig = 0;
        nsmall = (npts + 63) / 64;
    }
    nhrep_main<<<nbig + nsmall, 512, 0, stream>>>(x, (float*)d_out, wsW, wsB,
                                                  npts, nbig);
}

// Round 9
// 182.764 us; speedup vs baseline: 2.6965x; 2.6965x over previous
//
#include <hip/hip_runtime.h>
#include <hip/hip_bf16.h>

// ---------------------------------------------------------------------------
// NHRepNet fused forward, Round 23: REVERT to R17 (session best, 103.4us).
//
// Final established model (R1-R22):
//  - R17 (96-pt, kk-sliced A/B stagger, Gch=8, depth-1 afr prefetch): 103.4us
//    kernel / 179.9us bench. Interleave proven (+12 vs phase-serial R14).
//  - R20 (poly softplus, -11us VALU): dur NULL -> VALU not critical.
//  - R21 (LDS-only barriers): NULL -> vmcnt drain was free (no cross-region
//    prefetch in flight).
//  - R18/R22 (Gch=4 variants, nominal 48-acc): catastrophic allocator spill
//    (460MB/971MB scratch). Any wave->tile mapping other than R17's
//    2-strip x 3-tile dual shape spills regardless of nominal arithmetic.
//    Gch=4 closed on 3 attempts.
//  - Structural floor: LDS pipe ~60% (62us/105), VALU ~50%, MFMA ~34%;
//    112 unified regs -> 2 blk/CU -> dependency stalls can't be hidden;
//    3 blk/CU needs <=85 regs = impossible with 48-acc dual. ~103-105us is
//    the floor of this design family.
// ---------------------------------------------------------------------------

using bf16x8 = __attribute__((ext_vector_type(8))) __bf16;
using f32x4  = __attribute__((ext_vector_type(4))) float;

#define LDA 264   // padded activation row stride (bf16)

#define OFFW0 0
#define OFFW1 8192
#define OFFW7 401408
#define WSB_BYTE_OFF 811008   // fp32 bias region
#define OFFB7 1792            // L0..L6 at l*256; L7 at 1792 (16 floats, padded)

#define SCALE_T2 144.26950408889634f      // 100*log2(e)
#define INV_SQRT2 0.70710678118654752f
#define LN2_100 0.0069314718055994531f    // ln2/100

__device__ __forceinline__ float fast_exp2(float x) {
#if __has_builtin(__builtin_amdgcn_exp2f)
    return __builtin_amdgcn_exp2f(x);
#else
    return exp2f(x);
#endif
}
__device__ __forceinline__ float fast_log2(float x) {
#if __has_builtin(__builtin_amdgcn_logf)
    return __builtin_amdgcn_logf(x);
#else
    return log2f(x);
#endif
}

// a2 = max(t2,0) + log2(1 + 2^-|t2|)   (t2-domain; scales folded into weights)
__device__ __forceinline__ float softplus_t2(float t2) {
    float e = fast_exp2(-fabsf(t2));
    float l = fast_log2(1.0f + e);
    return fmaxf(t2, 0.0f) + l;
}

__device__ __forceinline__ unsigned short bf16_rne(float f) {
    unsigned int u = __float_as_uint(f);
    unsigned int r = u + 0x7FFFu + ((u >> 16) & 1u);
    return (unsigned short)(r >> 16);
}

// ---------------------------------------------------------------------------
// Plain MFMA half (layer 0 only, KK=1). Wave owns ch [wave*32, wave*32+32).
// ---------------------------------------------------------------------------
template <int KK, int NTG>
__device__ __forceinline__ void mfma_group(
    const unsigned short* __restrict__ wfrag,
    const float* __restrict__ bias,
    const unsigned short* act,
    f32x4 (&acc)[2][NTG], int wave, int lane)
{
    const int quad = lane >> 4;
    const int l15  = lane & 15;

#pragma unroll
    for (int i = 0; i < 2; ++i) {
        const int chb = (wave * 2 + i) * 16 + quad * 4;
        const float4 b4 = *(const float4*)(bias + chb);
#pragma unroll
        for (int nt = 0; nt < NTG; ++nt)
            acc[i][nt] = f32x4{b4.x, b4.y, b4.z, b4.w};
    }

    const unsigned short* wbase = wfrag + (wave * 2 * KK * 64 + lane) * 8;

#pragma unroll
    for (int kk = 0; kk < KK; ++kk) {
        bf16x8 bfr[NTG];
#pragma unroll
        for (int nt = 0; nt < NTG; ++nt)
            bfr[nt] = *(const bf16x8*)(act + (nt * 16 + l15) * LDA + kk * 32 + quad * 8);
#pragma unroll
        for (int i = 0; i < 2; ++i) {
            bf16x8 afr = *(const bf16x8*)(wbase + (i * KK + kk) * 512);
#pragma unroll
            for (int nt = 0; nt < NTG; ++nt)
                acc[i][nt] = __builtin_amdgcn_mfma_f32_16x16x32_bf16(afr, bfr[nt], acc[i][nt], 0, 0, 0);
        }
    }
}

// Full epilogue of a group (used where no mfma to hide under).
template <int NTG>
__device__ __forceinline__ void epi_group_full(
    f32x4 (&acc)[2][NTG], unsigned short* act, const float* xst,
    int wave, int lane, bool splice)
{
    const int quad = lane >> 4;
    const int l15  = lane & 15;
#pragma unroll
    for (int i = 0; i < 2; ++i) {
        const int chb = (wave * 2 + i) * 16 + quad * 4;
#pragma unroll
        for (int nt = 0; nt < NTG; ++nt) {
            const int pt = nt * 16 + l15;
            float vv[4];
#pragma unroll
            for (int r = 0; r < 4; ++r)
                vv[r] = softplus_t2(acc[i][nt][r]);
            if (splice && chb == 252) {
                vv[1] = xst[pt * 4 + 0];
                vv[2] = xst[pt * 4 + 1];
                vv[3] = xst[pt * 4 + 2];
            }
            __hip_bfloat162 p01 = __float22bfloat162_rn(float2{vv[0], vv[1]});
            __hip_bfloat162 p23 = __float22bfloat162_rn(float2{vv[2], vv[3]});
            uint2 pk;
            pk.x = *(unsigned int*)&p01;
            pk.y = *(unsigned int*)&p23;
            *(uint2*)(act + pt * LDA + chb) = pk;
        }
    }
}

// ---------------------------------------------------------------------------
// Staggered region: build accX = W.actX + b while retiring accY (other
// group's previous-layer preacts) one slice per kk step. Slice VALU sits
// between bfr ds_reads and MFMAs (LDS-latency shadow); afr weight loads are
// explicitly prefetched one kk ahead (hidden under previous kk's MFMAs).
// ---------------------------------------------------------------------------
template <int KK, int NTG>
__device__ __forceinline__ void stag_region(
    const unsigned short* __restrict__ wfrag,
    const float* __restrict__ bias,
    const unsigned short* __restrict__ actX,
    unsigned short* actY,
    f32x4 (&accX)[2][NTG], f32x4 (&accY)[2][NTG],
    const float* xstY, bool splice, int wave, int lane)
{
    const int quad = lane >> 4;
    const int l15  = lane & 15;

#pragma unroll
    for (int i = 0; i < 2; ++i) {
        const int chb = (wave * 2 + i) * 16 + quad * 4;
        const float4 b4 = *(const float4*)(bias + chb);
#pragma unroll
        for (int nt = 0; nt < NTG; ++nt)
            accX[i][nt] = f32x4{b4.x, b4.y, b4.z, b4.w};
    }

    const unsigned short* wbase = wfrag + (wave * 2 * KK * 64 + lane) * 8;

    // depth-1 weight prefetch (L2 latency rides under previous kk's MFMAs)
    bf16x8 afr0 = *(const bf16x8*)(wbase);
    bf16x8 afr1 = *(const bf16x8*)(wbase + KK * 512);

#pragma unroll
    for (int kk = 0; kk < KK; ++kk) {
        const bf16x8 a0 = afr0, a1 = afr1;
        if (kk + 1 < KK) {
            afr0 = *(const bf16x8*)(wbase + (kk + 1) * 512);
            afr1 = *(const bf16x8*)(wbase + (KK + kk + 1) * 512);
        }

        bf16x8 bfr[NTG];
#pragma unroll
        for (int nt = 0; nt < NTG; ++nt)
            bfr[nt] = *(const bf16x8*)(actX + (nt * 16 + l15) * LDA + kk * 32 + quad * 8);

        if (kk < 2 * NTG) {   // one retired slice of group Y (compile-time idx)
            const int i  = kk & 1;       // constant under full unroll
            const int nt = kk >> 1;
            const int chb = (wave * 2 + i) * 16 + quad * 4;
            const int pt  = nt * 16 + l15;
            float vv[4];
#pragma unroll
            for (int r = 0; r < 4; ++r)
                vv[r] = softplus_t2(accY[i][nt][r]);
            if (splice && chb == 252) {   // ch 253..255 <- raw x
                vv[1] = xstY[pt * 4 + 0];
                vv[2] = xstY[pt * 4 + 1];
                vv[3] = xstY[pt * 4 + 2];
            }
            __hip_bfloat162 p01 = __float22bfloat162_rn(float2{vv[0], vv[1]});
            __hip_bfloat162 p23 = __float22bfloat162_rn(float2{vv[2], vv[3]});
            uint2 pk;
            pk.x = *(unsigned int*)&p01;
            pk.y = *(unsigned int*)&p23;
            *(uint2*)(actY + pt * LDA + chb) = pk;
        }

#pragma unroll
        for (int nt = 0; nt < NTG; ++nt)
            accX[0][nt] = __builtin_amdgcn_mfma_f32_16x16x32_bf16(a0, bfr[nt], accX[0][nt], 0, 0, 0);
#pragma unroll
        for (int nt = 0; nt < NTG; ++nt)
            accX[1][nt] = __builtin_amdgcn_mfma_f32_16x16x32_bf16(a1, bfr[nt], accX[1][nt], 0, 0, 0);
    }
}

// ---------------------------------------------------------------------------
// Layer 7 (256->8) for one 16-pt row block at row0; reduce + CSG + store.
// ---------------------------------------------------------------------------
__device__ __forceinline__ void l7_part(
    const unsigned short* act, const unsigned short* __restrict__ w7,
    const float* __restrict__ wsB, float* __restrict__ out,
    int row0, int ptg0, int npts, int lane)
{
    const int quad = lane >> 4, l15 = lane & 15;
    const float4 b4 = *(const float4*)(wsB + OFFB7 + quad * 4);  // quads>=2: zeros
    f32x4 acc = f32x4{b4.x, b4.y, b4.z, b4.w};
#pragma unroll
    for (int kk = 0; kk < 8; ++kk) {
        bf16x8 bfr = *(const bf16x8*)(act + (row0 + l15) * LDA + kk * 32 + quad * 8);
        bf16x8 afr = *(const bf16x8*)(w7 + (kk * 64 + lane) * 8);
        acc = __builtin_amdgcn_mfma_f32_16x16x32_bf16(afr, bfr, acc, 0, 0, 0);
    }
    // quad0 lanes hold ch0-3, quad1 ch4-7 for pt = row0+l15
    float u0 = __shfl(acc[0], l15 + 16);
    float u1 = __shfl(acc[1], l15 + 16);
    float u2 = __shfl(acc[2], l15 + 16);
    float u3 = __shfl(acc[3], l15 + 16);
    if (quad == 0) {
        const int ptg = ptg0 + l15;
        if (ptg < npts) {
            const float v0 = acc[0], v1 = acc[1], v2 = acc[2], v3 = acc[3];
            const float v4 = u0, v5 = u1, v6 = u2, v7 = u3;
            const float m23   = fminf(v2, v3);
            const float m67   = fmaxf(v6, v7);
            const float m4567 = fminf(fminf(v4, v5), m67);
            const float h     = fmaxf(fmaxf(v0, v1), fmaxf(m23, m4567));
            float* o = out + (long)ptg * 9;
            o[0] = h;
            o[1] = v0; o[2] = v1; o[3] = v2; o[4] = v3;
            o[5] = v4; o[6] = v5; o[7] = v6; o[8] = v7;
        }
    }
}

// ---------------------------------------------------------------------------
// Full network for one tile of 2*NTG*16 points (NTG=3 -> 96, NTG=1 -> 32),
// two staggered in-place groups A (rows 0..NTG*16) and B (rest). Schedule:
//   stage; bar
//   mfma_A(0); bar
//   mfma_B(0); epi_A(0); bar
//   l=1..6:  stag[mfma_A(l) + slices of accB(l-1)]; bar
//            stag[mfma_B(l) + slices of accA(l)];   bar
//   [L7(A) || epi_B(6)]; bar;  L7(B)
// ---------------------------------------------------------------------------
template <int NTG>
__device__ __forceinline__ void run_net(
    const float* __restrict__ x, float* __restrict__ out,
    const unsigned short* __restrict__ wsW, const float* __restrict__ wsB,
    unsigned short* act, float* xst,
    int base_pt, int npts, int tid)
{
    const int wave = tid >> 6, lane = tid & 63;

    // stage x into act channels 0..2, zero-pad to 32 (K-pad for layer 0)
    for (int i = tid; i < 2 * NTG * 16 * 32; i += 512) {
        const int pt = i >> 5, ch = i & 31;
        const int ptg = base_pt + pt;
        float v = 0.0f;
        if (ch < 3 && ptg < npts) v = x[ptg * 3 + ch];
        act[pt * LDA + ch] = bf16_rne(v);
        if (ch < 4) xst[pt * 4 + ch] = (ch < 3) ? v : 0.0f;
    }
    __syncthreads();

    unsigned short* actA = act;
    unsigned short* actB = act + NTG * 16 * LDA;
    const float* xstA = xst;
    const float* xstB = xst + NTG * 16 * 4;

    f32x4 accA[2][NTG], accB[2][NTG];

    // layer 0 (KK=1, tiny): A alone, then B with serial epi_A
    mfma_group<1, NTG>(wsW + OFFW0, wsB, actA, accA, wave, lane);
    __syncthreads();
    mfma_group<1, NTG>(wsW + OFFW0, wsB, actB, accB, wave, lane);
    epi_group_full<NTG>(accA, actA, xstA, wave, lane, false);
    __syncthreads();

    // layers 1..6, two staggered regions each
#pragma unroll 1
    for (int l = 1; l <= 6; ++l) {
        const unsigned short* Wl = wsW + OFFW1 + (l - 1) * 65536;
        const float* bl = wsB + l * 256;

        // mfma_A(l) + retire accB(l-1)  (splice when l-1 == 3)
        stag_region<8, NTG>(Wl, bl, actA, actB, accA, accB, xstB, l == 4, wave, lane);
        __syncthreads();

        // mfma_B(l) + retire accA(l)    (splice when l == 3)
        stag_region<8, NTG>(Wl, bl, actB, actA, accB, accA, xstA, l == 3, wave, lane);
        __syncthreads();
    }

    // [L7(A) || epi_B(6)]: actA finalized last region; epi writes actB only.
    if (wave < NTG)
        l7_part(act, wsW + OFFW7, wsB, out, wave * 16, base_pt + wave * 16, npts, lane);
    epi_group_full<NTG>(accB, actB, xstB, wave, lane, false);
    __syncthreads();

    // L7(B)
    if (wave < NTG)
        l7_part(act, wsW + OFFW7, wsB, out,
                NTG * 16 + wave * 16, base_pt + NTG * 16 + wave * 16, npts, lane);
}

__global__ __launch_bounds__(512, 4)
void nhrep_main(const float* __restrict__ x, float* __restrict__ out,
                const unsigned short* __restrict__ wsW,
                const float* __restrict__ wsB, int npts, int nbig)
{
    __shared__ unsigned short act[96 * LDA];   // 50688 B
    __shared__ float xst[96 * 4];              // 1536 B -> 52224 B total
    const int b = blockIdx.x;
    if (b < nbig) {
        run_net<3>(x, out, wsW, wsB, act, xst, b * 96, npts, threadIdx.x);
    } else {
        run_net<1>(x, out, wsW, wsB, act, xst,
                   nbig * 96 + (b - nbig) * 32, npts, threadIdx.x);
    }
}

// ---------------------------------------------------------------------------
// Fused prepack with scale folding (proven since R4, identity k-mapping).
// Frag (mt,kk,lane,j) = scale(l,k) * W^T[mt*16+(lane&15)][kk*32+(lane>>4)*8+j]
// ---------------------------------------------------------------------------
struct PackArgs {
    const float* W[8];
    const float* b[8];
};

#define TOTAL_FRAGS 50688
#define TOTAL_BIAS  1808

__global__ void prepack_all(PackArgs args, unsigned short* __restrict__ dstW,
                            float* __restrict__ dstB)
{
    const int t = blockIdx.x * blockDim.x + threadIdx.x;
    const int FB[9]  = {0, 1024, 9216, 17408, 25600, 33792, 41984, 50176, 50688};
    const int KKs[8] = {1, 8, 8, 8, 8, 8, 8, 8};
    const int ind[8] = {3, 256, 256, 256, 256, 256, 256, 256};
    const int outd[8]= {256, 256, 256, 253, 256, 256, 256, 8};

    if (t < TOTAL_FRAGS) {
        int l = 0;
        while (t >= FB[l + 1]) ++l;
        const int f    = t - FB[l];
        const int lane = f & 63;
        const int kk   = (f >> 6) % KKs[l];
        const int mt   = f / (64 * KKs[l]);
        const int o    = mt * 16 + (lane & 15);
        const int kb   = kk * 32 + (lane >> 4) * 8;
        const float* W = args.W[l];
        const int in_d = ind[l], out_d = outd[l];

        unsigned short v[8];
#pragma unroll
        for (int j = 0; j < 8; ++j) {
            const int k = kb + j;
            float w = 0.0f;
            if (k < in_d && o < out_d) {
                float sc = 1.0f;
                if (l == 0) sc = SCALE_T2;
                else if (l == 4) sc = (k < 253) ? INV_SQRT2 : (SCALE_T2 * INV_SQRT2);
                else if (l == 7) sc = LN2_100;
                w = W[k * out_d + o] * sc;
            }
            unsigned int u = __float_as_uint(w);
            v[j] = (unsigned short)((u + 0x7FFFu + ((u >> 16) & 1u)) >> 16);
        }
        uint4 p;
        p.x = (unsigned int)v[0] | ((unsigned int)v[1] << 16);
        p.y = (unsigned int)v[2] | ((unsigned int)v[3] << 16);
        p.z = (unsigned int)v[4] | ((unsigned int)v[5] << 16);
        p.w = (unsigned int)v[6] | ((unsigned int)v[7] << 16);
        *(uint4*)(dstW + (long)t * 8) = p;
    } else if (t < TOTAL_FRAGS + TOTAL_BIAS) {
        const int u = t - TOTAL_FRAGS;
        const int l = (u < 1792) ? (u >> 8) : 7;
        const int idx = (l < 7) ? (u & 255) : (u - 1792);
        const float sc = (l < 7) ? SCALE_T2 : 1.0f;   // b7 stays in output units
        dstB[u] = (idx < outd[l]) ? args.b[l][idx] * sc : 0.0f;
    }
}

extern "C" void kernel_launch(void* const* d_in, const int* in_sizes, int n_in,
                              void* d_out, int out_size, void* d_ws, size_t ws_size,
                              hipStream_t stream)
{
    const float* x = (const float*)d_in[0];
    unsigned short* wsW = (unsigned short*)d_ws;
    float* wsB = (float*)((char*)d_ws + WSB_BYTE_OFF);

    PackArgs pa;
    for (int l = 0; l < 8; ++l) {
        pa.W[l] = (const float*)d_in[1 + 2 * l];
        pa.b[l] = (const float*)d_in[2 + 2 * l];
    }
    const int ptot = TOTAL_FRAGS + TOTAL_BIAS;
    prepack_all<<<(ptot + 255) / 256, 256, 0, stream>>>(pa, wsW, wsB);

    const int npts = in_sizes[0] / 3;            // 100000
    // Mixed grid: 96-pt blocks for the bulk, 32-pt blocks for the drain tail.
    int nbig, nsmall;
    const int tail_pts = 16384;
    if (npts > tail_pts) {
        nbig = (npts - tail_pts + 95) / 96;      // 871
        const int base_small = nbig * 96;
        nsmall = (npts - base_small + 31) / 32;  // 512
    } else {
        nbig = 0;
        nsmall = (npts + 31) / 32;
    }
    nhrep_main<<<nbig + nsmall, 512, 0, stream>>>(x, (float*)d_out, wsW, wsB,
                                                  npts, nbig);
}